// Round 10
// baseline (719.811 us; speedup 1.0000x reference)
//
#include <hip/hip_runtime.h>
#include <stdint.h>

#define NPTS 16384
#define DIM  256
#define BK   64
#define MARGIN_R 1.5f            // in S-units; = 3.0 in D2 units; bf16 screen err <= ~0.2
#define CAPMAX 96
#define TWO_OVER_TAU (2.0f/0.07f)

using short8 = __attribute__((ext_vector_type(8))) short;
using f32x4  = __attribute__((ext_vector_type(4))) float;

__device__ __forceinline__ short f2bf(float f) {       // RTNE float->bf16
  unsigned u = __float_as_uint(f);
  u += 0x7FFFu + ((u >> 16) & 1u);
  return (short)(u >> 16);
}
__device__ __forceinline__ unsigned encf(float f) {
  unsigned u = __float_as_uint(f);
  return (u & 0x80000000u) ? ~u : (u | 0x80000000u);
}
__device__ __forceinline__ float decf(unsigned k) {
  return (k & 0x80000000u) ? __uint_as_float(k ^ 0x80000000u) : __uint_as_float(~k);
}

__device__ __forceinline__ void gload_lds16(const void* g, void* lds) {
  __builtin_amdgcn_global_load_lds(
      (const __attribute__((address_space(1))) unsigned int*)g,
      (__attribute__((address_space(3))) unsigned int*)lds, 16, 0, 0);
}

// ---------------- K0a: x2[j] = ||X_j||^2, init mkey/cnt ----------------
__global__ void k0_prep(const float* __restrict__ Xg, float* __restrict__ x2,
                        unsigned* __restrict__ mkey, unsigned* __restrict__ cnt) {
  int row = blockIdx.x * 4 + (threadIdx.x >> 6);
  int lane = threadIdx.x & 63;
  if (row >= NPTS) return;
  f32x4 xv = *(const f32x4*)&Xg[(size_t)row * DIM + lane * 4];
  float s = xv[0]*xv[0] + xv[1]*xv[1] + xv[2]*xv[2] + xv[3]*xv[3];
  #pragma unroll
  for (int m = 1; m < 64; m <<= 1) s += __shfl_xor(s, m, 64);
  if (lane == 0) {
    x2[row]  = s;
    mkey[row] = 0x00800000u;   // encf(-FLT_MAX)
    cnt[row]  = 0u;
  }
}

// ---------------- K0b: convert X,Y -> bf16 (same RTNE as validated rounds) ----
__global__ void k0_convert(const float* __restrict__ X, const float* __restrict__ Y,
                           short* __restrict__ Xb, short* __restrict__ Yb) {
  int b = blockIdx.x;
  const float* s; short* d;
  if (b < 2048) { s = X; d = Xb; } else { s = Y; d = Yb; b -= 2048; }
  size_t base = ((size_t)b * 256 + threadIdx.x) * 8;
  f32x4 v0 = *(const f32x4*)&s[base];
  f32x4 v1 = *(const f32x4*)&s[base + 4];
  short8 o;
  o[0]=f2bf(v0[0]); o[1]=f2bf(v0[1]); o[2]=f2bf(v0[2]); o[3]=f2bf(v0[3]);
  o[4]=f2bf(v1[0]); o[5]=f2bf(v1[1]); o[6]=f2bf(v1[2]); o[7]=f2bf(v1[3]);
  *(short8*)&d[base] = o;
}

// ---------------- K1 v6: bf16 MFMA screen, single-shot full-K staging ----------
// K=256 is too shallow to pipeline (r9 post-mortem: prologue+drain dominate,
// 4 K-steps never reach steady state). Instead: stage ALL of K at once
// (32 gload_lds/wave, outstanding=32<63), ONE __syncthreads, then 128 MFMAs
// with zero barriers (LDS read-only after fill). 128 KB LDS -> 1 block/CU
// (m201 precedent for 128KB static LDS on gfx950).
// Validated pieces byte-identical: XOR swizzle (conflicts=0), r5 block
// ordering, r7 non-blocking epilogue (mkey loads hoisted for ILP).
__global__ __launch_bounds__(256, 1) void k1_screen2(
    const short* __restrict__ Xb, const short* __restrict__ Yb,
    const float* __restrict__ x2g, unsigned* __restrict__ mkey,
    unsigned* __restrict__ cnt, unsigned* __restrict__ cand, int cap)
{
  __shared__ short As[4][128][BK];   // Y rows (bf16), swizzled slots, [ks][row][col]
  __shared__ short Bs[4][128][BK];   // X rows (bf16), swizzled slots
  const int tid  = threadIdx.x;
  const int lane = tid & 63, w = tid >> 6;
  const int wr = w >> 1, wc = w & 1;
  const int c = lane & 15, g = lane >> 4;

  // round-5 ordering: XCD-contiguous chunks; within XCD i-panel fast,
  // j-panel slow (16 j-panels per XCD, X panel L2-resident).
  int lin = blockIdx.x;
  int wg  = (lin & 7) * 2048 + (lin >> 3);
  const int i0 = (wg & 127) * 128;   // Y-row panel (fast)
  const int j0 = (wg >> 7) * 128;    // X-row panel (slow)

  f32x4 acc[4][4];
  #pragma unroll
  for (int m = 0; m < 4; ++m)
    #pragma unroll
    for (int n = 0; n < 4; ++n) acc[m][n] = f32x4{0.f, 0.f, 0.f, 0.f};

  // staging: wave w covers rows w*32+q*8+(lane>>3); global chunk is
  // (lane&7) XOR (lane>>3)  ->  LDS slot s of row r holds chunk s^(r&7).
  const int srow = w * 32 + (lane >> 3);
  const int scol = ((lane & 7) ^ (lane >> 3)) * 8;   // pre-swizzled source chunk
  const short* gA = Yb + (size_t)(i0 + srow) * DIM + scol;
  const short* gB = Xb + (size_t)(j0 + srow) * DIM + scol;

  // stage ALL of K: 4 k-panels x 4 row-quads x 2 arrays = 32 loads/wave
  #pragma unroll
  for (int ks = 0; ks < 4; ++ks) {
    #pragma unroll
    for (int q = 0; q < 4; ++q) {
      gload_lds16(gA + (size_t)q * 8 * DIM + ks * BK, &As[ks][w * 32 + q * 8][0]);
      gload_lds16(gB + (size_t)q * 8 * DIM + ks * BK, &Bs[ks][w * 32 + q * 8][0]);
    }
  }
  __syncthreads();                      // single fill barrier (vmcnt(0) here only)

  // full-K compute: 128 MFMAs, no barriers
  #pragma unroll
  for (int ks = 0; ks < 4; ++ks) {
    #pragma unroll
    for (int s = 0; s < 2; ++s) {
      short8 af[4], bb[4];
      #pragma unroll
      for (int m = 0; m < 4; ++m)
        af[m] = *(const short8*)&As[ks][wr * 64 + m * 16 + c][(((s * 4 + g) ^ (c & 7)) * 8)];
      #pragma unroll
      for (int n = 0; n < 4; ++n)
        bb[n] = *(const short8*)&Bs[ks][wc * 64 + n * 16 + c][(((s * 4 + g) ^ (c & 7)) * 8)];
      #pragma unroll
      for (int m = 0; m < 4; ++m)
        #pragma unroll
        for (int n = 0; n < 4; ++n)
          acc[m][n] = __builtin_amdgcn_mfma_f32_16x16x32_bf16(af[m], bb[n], acc[m][n], 0, 0, 0);
    }
  }

  // ---- epilogue: non-blocking threshold screen (r7 semantics, loads hoisted) ----
  float xh[4];
  #pragma unroll
  for (int n = 0; n < 4; ++n) xh[n] = 0.5f * x2g[j0 + wc * 64 + n * 16 + c];

  float fest[4][4];
  #pragma unroll
  for (int m = 0; m < 4; ++m)
    #pragma unroll
    for (int r = 0; r < 4; ++r)
      fest[m][r] = decf(mkey[i0 + wr * 64 + m * 16 + g * 4 + r]);  // 16 indep loads

  #pragma unroll
  for (int m = 0; m < 4; ++m) {
    #pragma unroll
    for (int r = 0; r < 4; ++r) {
      float R0 = acc[m][0][r] - xh[0];
      float R1 = acc[m][1][r] - xh[1];
      float R2 = acc[m][2][r] - xh[2];
      float R3 = acc[m][3][r] - xh[3];
      float rm = fmaxf(fmaxf(R0, R1), fmaxf(R2, R3));
      rm = fmaxf(rm, __shfl_xor(rm, 1, 64));
      rm = fmaxf(rm, __shfl_xor(rm, 2, 64));
      rm = fmaxf(rm, __shfl_xor(rm, 4, 64));
      rm = fmaxf(rm, __shfl_xor(rm, 8, 64));   // uniform within 16-lane group
      int row = i0 + wr * 64 + m * 16 + g * 4 + r;
      float fe = fest[m][r];
      float thr = fmaxf(fe, rm) - MARGIN_R;
      if (c == 0 && rm > fe) atomicMax(&mkey[row], encf(rm));  // fire-and-forget
      #pragma unroll
      for (int n = 0; n < 4; ++n) {
        float Rv = (n == 0) ? R0 : (n == 1) ? R1 : (n == 2) ? R2 : R3;
        if (Rv > thr) {
          int col = j0 + wc * 64 + n * 16 + c;
          unsigned pos = atomicAdd(&cnt[row], 1u);
          if (pos < (unsigned)cap) cand[(size_t)row * cap + pos] = (unsigned)col;
        }
      }
    }
  }
}

// ---------------- K1 fallback (f32 reg-staged, validated round 3) ----------------
#define LDA 72
__global__ __launch_bounds__(256, 2) void k1_screen_f32(
    const float* __restrict__ Xg, const float* __restrict__ Yg,
    const float* __restrict__ x2g, unsigned* __restrict__ mkey,
    unsigned* __restrict__ cnt, unsigned* __restrict__ cand, int cap)
{
  __shared__ short As[2][128][LDA];
  __shared__ short Bs[2][128][LDA];
  const int tid  = threadIdx.x;
  const int lane = tid & 63, wid = tid >> 6;
  const int wr = wid >> 1, wc = wid & 1;
  const int c = lane & 15, g = lane >> 4;
  const int i0 = blockIdx.x * 128;
  const int j0 = blockIdx.y * 128;

  f32x4 acc[4][4];
  #pragma unroll
  for (int m = 0; m < 4; ++m)
    #pragma unroll
    for (int n = 0; n < 4; ++n) acc[m][n] = f32x4{0.f, 0.f, 0.f, 0.f};

  const int skc = tid & 7;
  f32x4 ra[4][2], rb[4][2];

  auto loadRegs = [&](int ks) {
    #pragma unroll
    for (int t = 0; t < 4; ++t) {
      int r = t * 32 + (tid >> 3);
      const float* pa = &Yg[(size_t)(i0 + r) * DIM + ks * 64 + skc * 8];
      const float* pb = &Xg[(size_t)(j0 + r) * DIM + ks * 64 + skc * 8];
      ra[t][0] = *(const f32x4*)pa;  ra[t][1] = *(const f32x4*)(pa + 4);
      rb[t][0] = *(const f32x4*)pb;  rb[t][1] = *(const f32x4*)(pb + 4);
    }
  };
  auto writeRegs = [&](int buf) {
    #pragma unroll
    for (int t = 0; t < 4; ++t) {
      int r = t * 32 + (tid >> 3);
      short8 a8, b8;
      #pragma unroll
      for (int e = 0; e < 8; ++e) {
        a8[e] = f2bf(ra[t][e >> 2][e & 3]);
        b8[e] = f2bf(rb[t][e >> 2][e & 3]);
      }
      *(short8*)&As[buf][r][skc * 8] = a8;
      *(short8*)&Bs[buf][r][skc * 8] = b8;
    }
  };
  auto computeT = [&](int buf) {
    #pragma unroll
    for (int s = 0; s < 2; ++s) {
      short8 af[4], bb[4];
      #pragma unroll
      for (int m = 0; m < 4; ++m)
        af[m] = *(const short8*)&As[buf][wr * 64 + m * 16 + c][s * 32 + g * 8];
      #pragma unroll
      for (int n = 0; n < 4; ++n)
        bb[n] = *(const short8*)&Bs[buf][wc * 64 + n * 16 + c][s * 32 + g * 8];
      #pragma unroll
      for (int m = 0; m < 4; ++m)
        #pragma unroll
        for (int n = 0; n < 4; ++n)
          acc[m][n] = __builtin_amdgcn_mfma_f32_16x16x32_bf16(af[m], bb[n], acc[m][n], 0, 0, 0);
    }
  };

  loadRegs(0); writeRegs(0);
  __syncthreads();
  for (int ks = 0; ks < 4; ++ks) {
    if (ks < 3) loadRegs(ks + 1);
    computeT(ks & 1);
    if (ks < 3) writeRegs((ks + 1) & 1);
    __syncthreads();
  }

  float xh[4];
  #pragma unroll
  for (int n = 0; n < 4; ++n) xh[n] = 0.5f * x2g[j0 + wc * 64 + n * 16 + c];

  #pragma unroll
  for (int m = 0; m < 4; ++m) {
    #pragma unroll
    for (int r = 0; r < 4; ++r) {
      float R0 = acc[m][0][r] - xh[0];
      float R1 = acc[m][1][r] - xh[1];
      float R2 = acc[m][2][r] - xh[2];
      float R3 = acc[m][3][r] - xh[3];
      float rm = fmaxf(fmaxf(R0, R1), fmaxf(R2, R3));
      rm = fmaxf(rm, __shfl_xor(rm, 1, 64));
      rm = fmaxf(rm, __shfl_xor(rm, 2, 64));
      rm = fmaxf(rm, __shfl_xor(rm, 4, 64));
      rm = fmaxf(rm, __shfl_xor(rm, 8, 64));
      int row = i0 + wr * 64 + m * 16 + g * 4 + r;
      float thr = 0.f;
      if (c == 0) {
        float fest = decf(mkey[row]);
        thr = fest - MARGIN_R;
        if (rm > thr) {
          unsigned old = atomicMax(&mkey[row], encf(rm));
          float nm = fmaxf(decf(old), rm);
          thr = nm - MARGIN_R;
        }
      }
      thr = __shfl(thr, lane & 48, 64);
      #pragma unroll
      for (int n = 0; n < 4; ++n) {
        float Rv = (n == 0) ? R0 : (n == 1) ? R1 : (n == 2) ? R2 : R3;
        if (Rv > thr) {
          int col = j0 + wc * 64 + n * 16 + c;
          unsigned pos = atomicAdd(&cnt[row], 1u);
          if (pos < (unsigned)cap) cand[(size_t)row * cap + pos] = (unsigned)col;
        }
      }
    }
  }
}

// ---------------- K2: exact fp32 repair (one wave per row) ----------------
__global__ void k2_repair(const float* __restrict__ Xg, const float* __restrict__ Yg,
                          const float* __restrict__ x2g, const unsigned* __restrict__ cnt,
                          const unsigned* __restrict__ cand, int cap,
                          float* __restrict__ outp)
{
  int row = blockIdx.x * 4 + (threadIdx.x >> 6);
  int lane = threadIdx.x & 63;
  if (row >= NPTS) return;
  const f32x4 yv = *(const f32x4*)&Yg[(size_t)row * DIM + lane * 4];

  unsigned nc = cnt[row];
  bool brute = (nc > (unsigned)cap);
  int count = brute ? NPTS : (int)nc;

  float m = -3.4e38f, l = 0.f, bestS = -3.4e38f;
  int bestJ = 0x7fffffff;
  f32x4 o = {0.f, 0.f, 0.f, 0.f};

  for (int it = 0; it < count; ++it) {
    int j = brute ? it : (int)cand[(size_t)row * cap + it];
    const f32x4 xv = *(const f32x4*)&Xg[(size_t)j * DIM + lane * 4];
    float d = yv[0]*xv[0] + yv[1]*xv[1] + yv[2]*xv[2] + yv[3]*xv[3];
    #pragma unroll
    for (int s2 = 1; s2 < 64; s2 <<= 1) d += __shfl_xor(d, s2, 64);
    float S = d - 0.5f * x2g[j];
    if (S > bestS || (S == bestS && j < bestJ)) { bestS = S; bestJ = j; }
    if (S > m) {
      float a = expf((m - S) * TWO_OVER_TAU);
      l = l * a + 1.f;
      o = o * a + xv;
      m = S;
    } else {
      float w = expf((S - m) * TWO_OVER_TAU);
      l += w;
      o += w * xv;
    }
  }
  float invl = 1.f / l;
  f32x4 df;
  #pragma unroll
  for (int e = 0; e < 4; ++e) df[e] = yv[e] - o[e] * invl;
  float d2 = df[0]*df[0] + df[1]*df[1] + df[2]*df[2] + df[3]*df[3];
  #pragma unroll
  for (int s2 = 1; s2 < 64; s2 <<= 1) d2 += __shfl_xor(d2, s2, 64);
  if (lane == 0) {
    outp[row]        = sqrtf(d2);
    outp[NPTS + row] = (float)bestJ;
  }
}

// ---------------- last-resort brute force ----------------
__global__ void k_brute(const float* __restrict__ Xg, const float* __restrict__ Yg,
                        float* __restrict__ outp)
{
  int row = blockIdx.x * 4 + (threadIdx.x >> 6);
  int lane = threadIdx.x & 63;
  if (row >= NPTS) return;
  const f32x4 yv = *(const f32x4*)&Yg[(size_t)row * DIM + lane * 4];
  float m = -3.4e38f, l = 0.f, bestS = -3.4e38f;
  int bestJ = 0x7fffffff;
  f32x4 o = {0.f, 0.f, 0.f, 0.f};
  for (int j = 0; j < NPTS; ++j) {
    const f32x4 xv = *(const f32x4*)&Xg[(size_t)j * DIM + lane * 4];
    float d  = yv[0]*xv[0] + yv[1]*xv[1] + yv[2]*xv[2] + yv[3]*xv[3];
    float x2 = xv[0]*xv[0] + xv[1]*xv[1] + xv[2]*xv[2] + xv[3]*xv[3];
    #pragma unroll
    for (int s2 = 1; s2 < 64; s2 <<= 1) d  += __shfl_xor(d, s2, 64);
    #pragma unroll
    for (int s2 = 1; s2 < 64; s2 <<= 1) x2 += __shfl_xor(x2, s2, 64);
    float S = d - 0.5f * x2;
    if (S > bestS || (S == bestS && j < bestJ)) { bestS = S; bestJ = j; }
    if (S > m) {
      float a = expf((m - S) * TWO_OVER_TAU);
      l = l * a + 1.f; o = o * a + xv; m = S;
    } else {
      float w = expf((S - m) * TWO_OVER_TAU);
      l += w; o += w * xv;
    }
  }
  float invl = 1.f / l;
  f32x4 df;
  #pragma unroll
  for (int e = 0; e < 4; ++e) df[e] = yv[e] - o[e] * invl;
  float d2 = df[0]*df[0] + df[1]*df[1] + df[2]*df[2] + df[3]*df[3];
  #pragma unroll
  for (int s2 = 1; s2 < 64; s2 <<= 1) d2 += __shfl_xor(d2, s2, 64);
  if (lane == 0) {
    outp[row]        = sqrtf(d2);
    outp[NPTS + row] = (float)bestJ;
  }
}

extern "C" void kernel_launch(void* const* d_in, const int* in_sizes, int n_in,
                              void* d_out, int out_size, void* d_ws, size_t ws_size,
                              hipStream_t stream) {
  const float* X = (const float*)d_in[0];
  const float* Y = (const float*)d_in[1];
  float* outp = (float*)d_out;

  // --- preferred layout: bf16 copies + screen metadata ---
  const size_t off_Xb   = 0;                         // 8 MB
  const size_t off_Yb   = 8388608;                   // 8 MB
  const size_t off_x2n  = 16777216;                  // 64 KB
  const size_t off_mkn  = 16842752;                  // 64 KB
  const size_t off_cntn = 16908288;                  // 64 KB
  const size_t off_cndn = 16973824;
  const size_t need_new = off_cndn + 32ull * NPTS * 4;   // cap >= 32

  if (ws_size >= need_new) {
    size_t cap_fit = (ws_size - off_cndn) / (4ull * NPTS);
    int cap = (int)((cap_fit < (size_t)CAPMAX) ? cap_fit : (size_t)CAPMAX);
    short*    Xb   = (short*)((char*)d_ws + off_Xb);
    short*    Yb   = (short*)((char*)d_ws + off_Yb);
    float*    x2   = (float*)((char*)d_ws + off_x2n);
    unsigned* mkey = (unsigned*)((char*)d_ws + off_mkn);
    unsigned* cnt  = (unsigned*)((char*)d_ws + off_cntn);
    unsigned* cand = (unsigned*)((char*)d_ws + off_cndn);

    k0_prep<<<dim3(NPTS / 4), dim3(256), 0, stream>>>(X, x2, mkey, cnt);
    k0_convert<<<dim3(4096), dim3(256), 0, stream>>>(X, Y, Xb, Yb);
    k1_screen2<<<dim3(16384), dim3(256), 0, stream>>>(Xb, Yb, x2, mkey, cnt, cand, cap);
    k2_repair<<<dim3(NPTS / 4), dim3(256), 0, stream>>>(X, Y, x2, cnt, cand, cap, outp);
    return;
  }

  // --- middle fallback: round-3 validated f32 path ---
  const size_t off_x2   = 0;
  const size_t off_mkey = 65536;
  const size_t off_cnt  = 131072;
  const size_t off_cand = 196608;
  const size_t need_min = off_cand + (size_t)NPTS * 4;

  if (ws_size < need_min) {
    k_brute<<<dim3(NPTS / 4), dim3(256), 0, stream>>>(X, Y, outp);
    return;
  }
  size_t cap_fit = (ws_size - off_cand) / (4ull * NPTS);
  int cap = (int)((cap_fit < (size_t)CAPMAX) ? cap_fit : (size_t)CAPMAX);

  float*    x2   = (float*)((char*)d_ws + off_x2);
  unsigned* mkey = (unsigned*)((char*)d_ws + off_mkey);
  unsigned* cnt  = (unsigned*)((char*)d_ws + off_cnt);
  unsigned* cand = (unsigned*)((char*)d_ws + off_cand);

  k0_prep<<<dim3(NPTS / 4), dim3(256), 0, stream>>>(X, x2, mkey, cnt);
  k1_screen_f32<<<dim3(128, 128), dim3(256), 0, stream>>>(X, Y, x2, mkey, cnt, cand, cap);
  k2_repair<<<dim3(NPTS / 4), dim3(256), 0, stream>>>(X, Y, x2, cnt, cand, cap, outp);
}

// Round 14
// 372.099 us; speedup vs baseline: 1.9345x; 1.9345x over previous
//
#include <hip/hip_runtime.h>
#include <stdint.h>

#define NPTS 16384
#define DIM  256
#define BK   64
#define MARGIN_R 1.5f            // in S-units; = 3.0 in D2 units; bf16 screen err <= ~0.2
#define CAPMAX 96
#define TWO_OVER_TAU (2.0f/0.07f)

using short8 = __attribute__((ext_vector_type(8))) short;
using f32x4  = __attribute__((ext_vector_type(4))) float;

__device__ __forceinline__ short f2bf(float f) {       // RTNE float->bf16
  unsigned u = __float_as_uint(f);
  u += 0x7FFFu + ((u >> 16) & 1u);
  return (short)(u >> 16);
}
__device__ __forceinline__ unsigned encf(float f) {
  unsigned u = __float_as_uint(f);
  return (u & 0x80000000u) ? ~u : (u | 0x80000000u);
}
__device__ __forceinline__ float decf(unsigned k) {
  return (k & 0x80000000u) ? __uint_as_float(k ^ 0x80000000u) : __uint_as_float(~k);
}

__device__ __forceinline__ void gload_lds16(const void* g, void* lds) {
  __builtin_amdgcn_global_load_lds(
      (const __attribute__((address_space(1))) unsigned int*)g,
      (__attribute__((address_space(3))) unsigned int*)lds, 16, 0, 0);
}

// ---------------- K0a: x2[j] = ||X_j||^2, init mkey/cnt ----------------
__global__ void k0_prep(const float* __restrict__ Xg, float* __restrict__ x2,
                        unsigned* __restrict__ mkey, unsigned* __restrict__ cnt) {
  int row = blockIdx.x * 4 + (threadIdx.x >> 6);
  int lane = threadIdx.x & 63;
  if (row >= NPTS) return;
  f32x4 xv = *(const f32x4*)&Xg[(size_t)row * DIM + lane * 4];
  float s = xv[0]*xv[0] + xv[1]*xv[1] + xv[2]*xv[2] + xv[3]*xv[3];
  #pragma unroll
  for (int m = 1; m < 64; m <<= 1) s += __shfl_xor(s, m, 64);
  if (lane == 0) {
    x2[row]  = s;
    mkey[row] = 0x00800000u;   // encf(-FLT_MAX)
    cnt[row]  = 0u;
  }
}

// ---------------- K0b: convert X,Y -> bf16 (same RTNE as validated rounds) ----
__global__ void k0_convert(const float* __restrict__ X, const float* __restrict__ Y,
                           short* __restrict__ Xb, short* __restrict__ Yb) {
  int b = blockIdx.x;
  const float* s; short* d;
  if (b < 2048) { s = X; d = Xb; } else { s = Y; d = Yb; b -= 2048; }
  size_t base = ((size_t)b * 256 + threadIdx.x) * 8;
  f32x4 v0 = *(const f32x4*)&s[base];
  f32x4 v1 = *(const f32x4*)&s[base + 4];
  short8 o;
  o[0]=f2bf(v0[0]); o[1]=f2bf(v0[1]); o[2]=f2bf(v0[2]); o[3]=f2bf(v0[3]);
  o[4]=f2bf(v1[0]); o[5]=f2bf(v1[1]); o[6]=f2bf(v1[2]); o[7]=f2bf(v1[3]);
  *(short8*)&d[base] = o;
}

// ---------------- K1 v7: bf16 MFMA screen, 4 blocks/CU occupancy ----------------
// r10 post-mortem: kernel is latency-exposure-bound; per-block serial cost is
// ~constant across r7/r9/r10 — only TLP (resident blocks/CU) moves the time.
// So: single-buffer [128][64] x2 = 32 KB LDS -> 4 blocks/CU (16 waves, 4/SIMD).
// stage -> sync -> compute -> sync. No intra-block prefetch (K=256 too shallow
// to pipeline — proven r9/r10); overlap comes from 4 resident blocks.
// Validated pieces byte-identical: XOR swizzle (conflicts=0), r5 block
// ordering, r7/r10 non-blocking epilogue with hoisted fest loads.
__global__ __launch_bounds__(256, 4) void k1_screen2(
    const short* __restrict__ Xb, const short* __restrict__ Yb,
    const float* __restrict__ x2g, unsigned* __restrict__ mkey,
    unsigned* __restrict__ cnt, unsigned* __restrict__ cand, int cap)
{
  __shared__ short As[128][BK];   // Y rows (bf16), swizzled slots
  __shared__ short Bs[128][BK];   // X rows (bf16), swizzled slots
  const int tid  = threadIdx.x;
  const int lane = tid & 63, w = tid >> 6;
  const int wr = w >> 1, wc = w & 1;
  const int c = lane & 15, g = lane >> 4;

  // round-5 ordering: XCD-contiguous chunks; within XCD i-panel fast,
  // j-panel slow (16 j-panels per XCD, X panel L2-resident).
  int lin = blockIdx.x;
  int wg  = (lin & 7) * 2048 + (lin >> 3);
  const int i0 = (wg & 127) * 128;   // Y-row panel (fast)
  const int j0 = (wg >> 7) * 128;    // X-row panel (slow)

  f32x4 acc[4][4];
  #pragma unroll
  for (int m = 0; m < 4; ++m)
    #pragma unroll
    for (int n = 0; n < 4; ++n) acc[m][n] = f32x4{0.f, 0.f, 0.f, 0.f};

  // staging: wave w covers rows w*32+q*8+(lane>>3); global chunk is
  // (lane&7) XOR (lane>>3)  ->  LDS slot s of row r holds chunk s^(r&7).
  const int srow = w * 32 + (lane >> 3);
  const int scol = ((lane & 7) ^ (lane >> 3)) * 8;   // pre-swizzled source chunk
  const short* gA = Yb + (size_t)(i0 + srow) * DIM + scol;
  const short* gB = Xb + (size_t)(j0 + srow) * DIM + scol;

  auto stage = [&](int ks) {
    #pragma unroll
    for (int q = 0; q < 4; ++q) {
      gload_lds16(gA + (size_t)q * 8 * DIM + ks * BK, &As[w * 32 + q * 8][0]);
      gload_lds16(gB + (size_t)q * 8 * DIM + ks * BK, &Bs[w * 32 + q * 8][0]);
    }
  };
  auto computeT = [&]() {
    #pragma unroll
    for (int s = 0; s < 2; ++s) {
      short8 af[4], bb[4];
      #pragma unroll
      for (int m = 0; m < 4; ++m)
        af[m] = *(const short8*)&As[wr * 64 + m * 16 + c][(((s * 4 + g) ^ (c & 7)) * 8)];
      #pragma unroll
      for (int n = 0; n < 4; ++n)
        bb[n] = *(const short8*)&Bs[wc * 64 + n * 16 + c][(((s * 4 + g) ^ (c & 7)) * 8)];
      #pragma unroll
      for (int m = 0; m < 4; ++m)
        #pragma unroll
        for (int n = 0; n < 4; ++n)
          acc[m][n] = __builtin_amdgcn_mfma_f32_16x16x32_bf16(af[m], bb[n], acc[m][n], 0, 0, 0);
    }
  };

  #pragma unroll
  for (int ks = 0; ks < 4; ++ks) {
    stage(ks);
    __syncthreads();        // all loads landed (vmcnt(0) + barrier)
    computeT();
    if (ks < 3) __syncthreads();   // WAR: done reading before next stage
  }

  // ---- epilogue: non-blocking threshold screen (r7/r10 semantics) ----
  float xh[4];
  #pragma unroll
  for (int n = 0; n < 4; ++n) xh[n] = 0.5f * x2g[j0 + wc * 64 + n * 16 + c];

  float fest[4][4];
  #pragma unroll
  for (int m = 0; m < 4; ++m)
    #pragma unroll
    for (int r = 0; r < 4; ++r)
      fest[m][r] = decf(mkey[i0 + wr * 64 + m * 16 + g * 4 + r]);  // 16 indep loads

  #pragma unroll
  for (int m = 0; m < 4; ++m) {
    #pragma unroll
    for (int r = 0; r < 4; ++r) {
      float R0 = acc[m][0][r] - xh[0];
      float R1 = acc[m][1][r] - xh[1];
      float R2 = acc[m][2][r] - xh[2];
      float R3 = acc[m][3][r] - xh[3];
      float rm = fmaxf(fmaxf(R0, R1), fmaxf(R2, R3));
      rm = fmaxf(rm, __shfl_xor(rm, 1, 64));
      rm = fmaxf(rm, __shfl_xor(rm, 2, 64));
      rm = fmaxf(rm, __shfl_xor(rm, 4, 64));
      rm = fmaxf(rm, __shfl_xor(rm, 8, 64));   // uniform within 16-lane group
      int row = i0 + wr * 64 + m * 16 + g * 4 + r;
      float fe = fest[m][r];
      float thr = fmaxf(fe, rm) - MARGIN_R;
      if (c == 0 && rm > fe) atomicMax(&mkey[row], encf(rm));  // fire-and-forget
      #pragma unroll
      for (int n = 0; n < 4; ++n) {
        float Rv = (n == 0) ? R0 : (n == 1) ? R1 : (n == 2) ? R2 : R3;
        if (Rv > thr) {
          int col = j0 + wc * 64 + n * 16 + c;
          unsigned pos = atomicAdd(&cnt[row], 1u);
          if (pos < (unsigned)cap) cand[(size_t)row * cap + pos] = (unsigned)col;
        }
      }
    }
  }
}

// ---------------- K1 fallback (f32 reg-staged, validated round 3) ----------------
#define LDA 72
__global__ __launch_bounds__(256, 2) void k1_screen_f32(
    const float* __restrict__ Xg, const float* __restrict__ Yg,
    const float* __restrict__ x2g, unsigned* __restrict__ mkey,
    unsigned* __restrict__ cnt, unsigned* __restrict__ cand, int cap)
{
  __shared__ short As[2][128][LDA];
  __shared__ short Bs[2][128][LDA];
  const int tid  = threadIdx.x;
  const int lane = tid & 63, wid = tid >> 6;
  const int wr = wid >> 1, wc = wid & 1;
  const int c = lane & 15, g = lane >> 4;
  const int i0 = blockIdx.x * 128;
  const int j0 = blockIdx.y * 128;

  f32x4 acc[4][4];
  #pragma unroll
  for (int m = 0; m < 4; ++m)
    #pragma unroll
    for (int n = 0; n < 4; ++n) acc[m][n] = f32x4{0.f, 0.f, 0.f, 0.f};

  const int skc = tid & 7;
  f32x4 ra[4][2], rb[4][2];

  auto loadRegs = [&](int ks) {
    #pragma unroll
    for (int t = 0; t < 4; ++t) {
      int r = t * 32 + (tid >> 3);
      const float* pa = &Yg[(size_t)(i0 + r) * DIM + ks * 64 + skc * 8];
      const float* pb = &Xg[(size_t)(j0 + r) * DIM + ks * 64 + skc * 8];
      ra[t][0] = *(const f32x4*)pa;  ra[t][1] = *(const f32x4*)(pa + 4);
      rb[t][0] = *(const f32x4*)pb;  rb[t][1] = *(const f32x4*)(pb + 4);
    }
  };
  auto writeRegs = [&](int buf) {
    #pragma unroll
    for (int t = 0; t < 4; ++t) {
      int r = t * 32 + (tid >> 3);
      short8 a8, b8;
      #pragma unroll
      for (int e = 0; e < 8; ++e) {
        a8[e] = f2bf(ra[t][e >> 2][e & 3]);
        b8[e] = f2bf(rb[t][e >> 2][e & 3]);
      }
      *(short8*)&As[buf][r][skc * 8] = a8;
      *(short8*)&Bs[buf][r][skc * 8] = b8;
    }
  };
  auto computeT = [&](int buf) {
    #pragma unroll
    for (int s = 0; s < 2; ++s) {
      short8 af[4], bb[4];
      #pragma unroll
      for (int m = 0; m < 4; ++m)
        af[m] = *(const short8*)&As[buf][wr * 64 + m * 16 + c][s * 32 + g * 8];
      #pragma unroll
      for (int n = 0; n < 4; ++n)
        bb[n] = *(const short8*)&Bs[buf][wc * 64 + n * 16 + c][s * 32 + g * 8];
      #pragma unroll
      for (int m = 0; m < 4; ++m)
        #pragma unroll
        for (int n = 0; n < 4; ++n)
          acc[m][n] = __builtin_amdgcn_mfma_f32_16x16x32_bf16(af[m], bb[n], acc[m][n], 0, 0, 0);
    }
  };

  loadRegs(0); writeRegs(0);
  __syncthreads();
  for (int ks = 0; ks < 4; ++ks) {
    if (ks < 3) loadRegs(ks + 1);
    computeT(ks & 1);
    if (ks < 3) writeRegs((ks + 1) & 1);
    __syncthreads();
  }

  float xh[4];
  #pragma unroll
  for (int n = 0; n < 4; ++n) xh[n] = 0.5f * x2g[j0 + wc * 64 + n * 16 + c];

  #pragma unroll
  for (int m = 0; m < 4; ++m) {
    #pragma unroll
    for (int r = 0; r < 4; ++r) {
      float R0 = acc[m][0][r] - xh[0];
      float R1 = acc[m][1][r] - xh[1];
      float R2 = acc[m][2][r] - xh[2];
      float R3 = acc[m][3][r] - xh[3];
      float rm = fmaxf(fmaxf(R0, R1), fmaxf(R2, R3));
      rm = fmaxf(rm, __shfl_xor(rm, 1, 64));
      rm = fmaxf(rm, __shfl_xor(rm, 2, 64));
      rm = fmaxf(rm, __shfl_xor(rm, 4, 64));
      rm = fmaxf(rm, __shfl_xor(rm, 8, 64));
      int row = i0 + wr * 64 + m * 16 + g * 4 + r;
      float thr = 0.f;
      if (c == 0) {
        float fest = decf(mkey[row]);
        thr = fest - MARGIN_R;
        if (rm > thr) {
          unsigned old = atomicMax(&mkey[row], encf(rm));
          float nm = fmaxf(decf(old), rm);
          thr = nm - MARGIN_R;
        }
      }
      thr = __shfl(thr, lane & 48, 64);
      #pragma unroll
      for (int n = 0; n < 4; ++n) {
        float Rv = (n == 0) ? R0 : (n == 1) ? R1 : (n == 2) ? R2 : R3;
        if (Rv > thr) {
          int col = j0 + wc * 64 + n * 16 + c;
          unsigned pos = atomicAdd(&cnt[row], 1u);
          if (pos < (unsigned)cap) cand[(size_t)row * cap + pos] = (unsigned)col;
        }
      }
    }
  }
}

// ---------------- K2: exact fp32 repair (one wave per row) ----------------
__global__ void k2_repair(const float* __restrict__ Xg, const float* __restrict__ Yg,
                          const float* __restrict__ x2g, const unsigned* __restrict__ cnt,
                          const unsigned* __restrict__ cand, int cap,
                          float* __restrict__ outp)
{
  int row = blockIdx.x * 4 + (threadIdx.x >> 6);
  int lane = threadIdx.x & 63;
  if (row >= NPTS) return;
  const f32x4 yv = *(const f32x4*)&Yg[(size_t)row * DIM + lane * 4];

  unsigned nc = cnt[row];
  bool brute = (nc > (unsigned)cap);
  int count = brute ? NPTS : (int)nc;

  float m = -3.4e38f, l = 0.f, bestS = -3.4e38f;
  int bestJ = 0x7fffffff;
  f32x4 o = {0.f, 0.f, 0.f, 0.f};

  for (int it = 0; it < count; ++it) {
    int j = brute ? it : (int)cand[(size_t)row * cap + it];
    const f32x4 xv = *(const f32x4*)&Xg[(size_t)j * DIM + lane * 4];
    float d = yv[0]*xv[0] + yv[1]*xv[1] + yv[2]*xv[2] + yv[3]*xv[3];
    #pragma unroll
    for (int s2 = 1; s2 < 64; s2 <<= 1) d += __shfl_xor(d, s2, 64);
    float S = d - 0.5f * x2g[j];
    if (S > bestS || (S == bestS && j < bestJ)) { bestS = S; bestJ = j; }
    if (S > m) {
      float a = expf((m - S) * TWO_OVER_TAU);
      l = l * a + 1.f;
      o = o * a + xv;
      m = S;
    } else {
      float w = expf((S - m) * TWO_OVER_TAU);
      l += w;
      o += w * xv;
    }
  }
  float invl = 1.f / l;
  f32x4 df;
  #pragma unroll
  for (int e = 0; e < 4; ++e) df[e] = yv[e] - o[e] * invl;
  float d2 = df[0]*df[0] + df[1]*df[1] + df[2]*df[2] + df[3]*df[3];
  #pragma unroll
  for (int s2 = 1; s2 < 64; s2 <<= 1) d2 += __shfl_xor(d2, s2, 64);
  if (lane == 0) {
    outp[row]        = sqrtf(d2);
    outp[NPTS + row] = (float)bestJ;
  }
}

// ---------------- last-resort brute force ----------------
__global__ void k_brute(const float* __restrict__ Xg, const float* __restrict__ Yg,
                        float* __restrict__ outp)
{
  int row = blockIdx.x * 4 + (threadIdx.x >> 6);
  int lane = threadIdx.x & 63;
  if (row >= NPTS) return;
  const f32x4 yv = *(const f32x4*)&Yg[(size_t)row * DIM + lane * 4];
  float m = -3.4e38f, l = 0.f, bestS = -3.4e38f;
  int bestJ = 0x7fffffff;
  f32x4 o = {0.f, 0.f, 0.f, 0.f};
  for (int j = 0; j < NPTS; ++j) {
    const f32x4 xv = *(const f32x4*)&Xg[(size_t)j * DIM + lane * 4];
    float d  = yv[0]*xv[0] + yv[1]*xv[1] + yv[2]*xv[2] + yv[3]*xv[3];
    float x2 = xv[0]*xv[0] + xv[1]*xv[1] + xv[2]*xv[2] + xv[3]*xv[3];
    #pragma unroll
    for (int s2 = 1; s2 < 64; s2 <<= 1) d  += __shfl_xor(d, s2, 64);
    #pragma unroll
    for (int s2 = 1; s2 < 64; s2 <<= 1) x2 += __shfl_xor(x2, s2, 64);
    float S = d - 0.5f * x2;
    if (S > bestS || (S == bestS && j < bestJ)) { bestS = S; bestJ = j; }
    if (S > m) {
      float a = expf((m - S) * TWO_OVER_TAU);
      l = l * a + 1.f; o = o * a + xv; m = S;
    } else {
      float w = expf((S - m) * TWO_OVER_TAU);
      l += w; o += w * xv;
    }
  }
  float invl = 1.f / l;
  f32x4 df;
  #pragma unroll
  for (int e = 0; e < 4; ++e) df[e] = yv[e] - o[e] * invl;
  float d2 = df[0]*df[0] + df[1]*df[1] + df[2]*df[2] + df[3]*df[3];
  #pragma unroll
  for (int s2 = 1; s2 < 64; s2 <<= 1) d2 += __shfl_xor(d2, s2, 64);
  if (lane == 0) {
    outp[row]        = sqrtf(d2);
    outp[NPTS + row] = (float)bestJ;
  }
}

extern "C" void kernel_launch(void* const* d_in, const int* in_sizes, int n_in,
                              void* d_out, int out_size, void* d_ws, size_t ws_size,
                              hipStream_t stream) {
  const float* X = (const float*)d_in[0];
  const float* Y = (const float*)d_in[1];
  float* outp = (float*)d_out;

  // --- preferred layout: bf16 copies + screen metadata ---
  const size_t off_Xb   = 0;                         // 8 MB
  const size_t off_Yb   = 8388608;                   // 8 MB
  const size_t off_x2n  = 16777216;                  // 64 KB
  const size_t off_mkn  = 16842752;                  // 64 KB
  const size_t off_cntn = 16908288;                  // 64 KB
  const size_t off_cndn = 16973824;
  const size_t need_new = off_cndn + 32ull * NPTS * 4;   // cap >= 32

  if (ws_size >= need_new) {
    size_t cap_fit = (ws_size - off_cndn) / (4ull * NPTS);
    int cap = (int)((cap_fit < (size_t)CAPMAX) ? cap_fit : (size_t)CAPMAX);
    short*    Xb   = (short*)((char*)d_ws + off_Xb);
    short*    Yb   = (short*)((char*)d_ws + off_Yb);
    float*    x2   = (float*)((char*)d_ws + off_x2n);
    unsigned* mkey = (unsigned*)((char*)d_ws + off_mkn);
    unsigned* cnt  = (unsigned*)((char*)d_ws + off_cntn);
    unsigned* cand = (unsigned*)((char*)d_ws + off_cndn);

    k0_prep<<<dim3(NPTS / 4), dim3(256), 0, stream>>>(X, x2, mkey, cnt);
    k0_convert<<<dim3(4096), dim3(256), 0, stream>>>(X, Y, Xb, Yb);
    k1_screen2<<<dim3(16384), dim3(256), 0, stream>>>(Xb, Yb, x2, mkey, cnt, cand, cap);
    k2_repair<<<dim3(NPTS / 4), dim3(256), 0, stream>>>(X, Y, x2, cnt, cand, cap, outp);
    return;
  }

  // --- middle fallback: round-3 validated f32 path ---
  const size_t off_x2   = 0;
  const size_t off_mkey = 65536;
  const size_t off_cnt  = 131072;
  const size_t off_cand = 196608;
  const size_t need_min = off_cand + (size_t)NPTS * 4;

  if (ws_size < need_min) {
    k_brute<<<dim3(NPTS / 4), dim3(256), 0, stream>>>(X, Y, outp);
    return;
  }
  size_t cap_fit = (ws_size - off_cand) / (4ull * NPTS);
  int cap = (int)((cap_fit < (size_t)CAPMAX) ? cap_fit : (size_t)CAPMAX);

  float*    x2   = (float*)((char*)d_ws + off_x2);
  unsigned* mkey = (unsigned*)((char*)d_ws + off_mkey);
  unsigned* cnt  = (unsigned*)((char*)d_ws + off_cnt);
  unsigned* cand = (unsigned*)((char*)d_ws + off_cand);

  k0_prep<<<dim3(NPTS / 4), dim3(256), 0, stream>>>(X, x2, mkey, cnt);
  k1_screen_f32<<<dim3(128, 128), dim3(256), 0, stream>>>(X, Y, x2, mkey, cnt, cand, cap);
  k2_repair<<<dim3(NPTS / 4), dim3(256), 0, stream>>>(X, Y, x2, cnt, cand, cap, outp);
}